// Round 6
// baseline (26.336 us; speedup 1.0000x reference)
//
#include <hip/hip_runtime.h>
#include <cmath>

#define HDIM 128
typedef float f32x2 __attribute__((ext_vector_type(2)));

constexpr float EPSF = 1e-5f;
constexpr float K2L  = 2.8853900817779268f;   // 2*log2(e)
constexpr float INVK = 0.34657359027997264f;  // ln(2)/2
constexpr float L2E  = 1.4426950408889634f;   // log2(e)
constexpr float LN2  = 0.6931471805599453f;
constexpr float UXXS = -2.0f * INVK * INVK;   // restores -2*c^2 scale in epilogue
constexpr unsigned long long MAGIC = 0x7A3C9E51ULL << 32;

__device__ inline float fast_rcp(float x) { return __builtin_amdgcn_rcpf(x); }

__device__ inline float fast_exp2(float x) {
#if __has_builtin(__builtin_amdgcn_exp2f)
    return __builtin_amdgcn_exp2f(x);
#else
    float r; asm("v_exp_f32 %0, %1" : "=v"(r) : "v"(x)); return r;
#endif
}

__device__ inline float fast_log2(float x) {
#if __has_builtin(__builtin_amdgcn_logf)
    return __builtin_amdgcn_logf(x);
#else
    float r; asm("v_log_f32 %0, %1" : "=v"(r) : "v"(x)); return r;
#endif
}

__device__ inline f32x2 splat2(float v) { return (f32x2){v, v}; }

__device__ inline f32x2 pk_fma(f32x2 a, f32x2 b, f32x2 c) {
#if __has_builtin(__builtin_elementwise_fma)
    return __builtin_elementwise_fma(a, b, c);
#else
    f32x2 r; r.x = fmaf(a.x, b.x, c.x); r.y = fmaf(a.y, b.y, c.y); return r;
#endif
}

__device__ inline double wave_reduce(double v) {
    #pragma unroll
    for (int off = 32; off > 0; off >>= 1)
        v += __shfl_down(v, off, 64);
    return v;
}

// ut,ux carry K2L scale; uxxp = +sum(wd*th*c'^2) carries K2L^2; UXXS restores -2/K2L^2.
__device__ inline void point_epilogue(float u, float ut, float ux, float uxxp,
                                      float x, float tgt,
                                      double& mspe, double& cal, double& bfly)
{
    const float q  = fast_exp2(-fabsf(u) * L2E);           // e^{-|u|}
    const float rp = fast_rcp(1.f + q);
    const float s  = (u >= 0.f) ? rp : q * rp;             // sigmoid(u)
    const float w_log  = fmaxf(u, 0.f) + LN2 * fast_log2(1.f + q);
    const float w_tail = q * fmaf(-0.5f, q, 1.f);          // softplus(u), u << 0
    const float w  = (u < -9.f) ? w_tail : w_log;

    const float utt  = ut * INVK;
    const float uxt  = ux * INVK;
    const float uxxt = uxxp * UXXS;
    const float w_t  = s * utt;
    const float w_x  = s * uxt;
    const float w_xx = fmaf(s * (1.f - s), uxt * uxt, s * uxxt);

    const float pe = (w - tgt) * fast_rcp(tgt + EPSF);
    mspe += (double)pe * (double)pe;

    const float ctm = fmaxf(-w_t, 0.f);
    cal += (double)ctm * (double)ctm;

    const float invw = fast_rcp(w);
    const float a1 = fmaf(-0.5f * x * w_x, invw, 1.f);
    const float g  = fmaf(0.5f, w_xx,
                     fmaf(a1, a1, -0.25f * w_x * (invw + 0.25f)));
    const float btm = fmaxf(-g, 0.f);
    bfly += (double)btm * (double)btm;
}

// Single dispatch: R1 pair-packed body + joint-rcp + poison-proof last-block reduce.
__global__ __launch_bounds__(256, 4) void surf_loss_fused(
    const float* __restrict__ tt, const float* __restrict__ xx,
    const float* __restrict__ tg,
    const float* __restrict__ W1, const float* __restrict__ b1,
    const float* __restrict__ W2, const float* __restrict__ b2,
    double* __restrict__ partials, unsigned long long* __restrict__ counter,
    float* __restrict__ out, int N)
{
    __shared__ float4 cs[HDIM];   // (A', C', B', W2), A',C',B' pre-scaled by K2L
    __shared__ double sred[3][4];
    __shared__ int lastflag;
    const int tid = threadIdx.x;

    // Block 0 is dispatched first and the whole grid is co-resident (<=1024
    // blocks, 32 VGPR, 2.2 KB LDS): publish the ticket base over the unknown
    // poison value before any block can possibly finish its body.
    if (blockIdx.x == 0 && tid == 0) {
        __hip_atomic_exchange(counter, MAGIC, __ATOMIC_RELAXED, __HIP_MEMORY_SCOPE_AGENT);
    }

    for (int i = tid; i < HDIM; i += 256) {
        cs[i] = make_float4(W1[i] * K2L, W1[HDIM + i] * K2L, b1[i] * K2L, W2[i]);
    }
    __syncthreads();
    const float b2v = b2[0];

    double mspe = 0.0, cal = 0.0, bfly = 0.0;

    const int npair = N >> 1;
    const f32x2* __restrict__ tt2 = (const f32x2*)tt;
    const f32x2* __restrict__ xx2 = (const f32x2*)xx;
    const f32x2* __restrict__ tg2 = (const f32x2*)tg;

    for (int p = blockIdx.x * 256 + tid; p < npair; p += gridDim.x * 256) {
        const f32x2 t2 = tt2[p], x2 = xx2[p], g2 = tg2[p];
        f32x2 u2   = splat2(0.f);
        f32x2 ut2  = splat2(0.f);
        f32x2 ux2  = splat2(0.f);
        f32x2 uxx2 = splat2(0.f);
        #pragma unroll 8
        for (int i = 0; i < HDIM; ++i) {
            const float4 c = cs[i];       // uniform index -> LDS broadcast, no conflict
            const f32x2 z  = pk_fma(t2, splat2(c.x),
                              pk_fma(x2, splat2(c.y), splat2(c.z)));  // 2z*log2(e)
            f32x2 e;  e.x = fast_exp2(z.x); e.y = fast_exp2(z.y);     // e^{2z}
            const f32x2 ep = e + splat2(1.f);
            // joint reciprocal: one v_rcp for both points
            const float R = fast_rcp(ep.x * ep.y);
            f32x2 r;  r.x = R * ep.y; r.y = R * ep.x;
            const f32x2 th = pk_fma(splat2(-2.f), r, splat2(1.f));    // tanh(z)
            const f32x2 d  = pk_fma(-th, th, splat2(1.f));            // sech^2(z)
            const f32x2 wd = d * splat2(c.w);
            u2   = pk_fma(th, splat2(c.w), u2);
            ut2  = pk_fma(wd, splat2(c.x), ut2);
            ux2  = pk_fma(wd, splat2(c.y), ux2);
            const f32x2 wt  = wd * th;
            const f32x2 wtc = wt * splat2(c.y);
            uxx2 = pk_fma(wtc, splat2(c.y), uxx2);                    // +sum wd*th*c'^2
        }
        point_epilogue(u2.x + b2v, ut2.x, ux2.x, uxx2.x, x2.x, g2.x, mspe, cal, bfly);
        point_epilogue(u2.y + b2v, ut2.y, ux2.y, uxx2.y, x2.y, g2.y, mspe, cal, bfly);
    }

    // odd-N tail: one scalar point
    if ((N & 1) && blockIdx.x == 0 && tid == 0) {
        const int idx = N - 1;
        const float t = tt[idx], x = xx[idx], tgt = tg[idx];
        float u = 0.f, ut = 0.f, ux = 0.f, uxx = 0.f;
        for (int i = 0; i < HDIM; ++i) {
            const float4 c = cs[i];
            const float zp = fmaf(t, c.x, fmaf(x, c.y, c.z));
            const float e  = fast_exp2(zp);
            const float r  = fast_rcp(e + 1.f);
            const float th = fmaf(-2.f, r, 1.f);
            const float d  = fmaf(-th, th, 1.f);
            const float wd = c.w * d;
            u   = fmaf(c.w, th, u);
            ut  = fmaf(wd, c.x, ut);
            ux  = fmaf(wd, c.y, ux);
            uxx = fmaf(wd * th * c.y, c.y, uxx);
        }
        point_epilogue(u + b2v, ut, ux, uxx, x, tgt, mspe, cal, bfly);
    }

    // block-level reduction -> partials
    double v0 = wave_reduce(mspe), v1 = wave_reduce(cal), v2 = wave_reduce(bfly);
    const int wid = tid >> 6, lane = tid & 63;
    if (lane == 0) { sred[0][wid] = v0; sred[1][wid] = v1; sred[2][wid] = v2; }
    __syncthreads();
    if (tid == 0) {
        double a = 0, b = 0, c = 0;
        #pragma unroll
        for (int wv = 0; wv < 4; ++wv) { a += sred[0][wv]; b += sred[1][wv]; c += sred[2][wv]; }
        partials[blockIdx.x * 3 + 0] = a;
        partials[blockIdx.x * 3 + 1] = b;
        partials[blockIdx.x * 3 + 2] = c;
        // ticket: wait for block 0's MAGIC base (instant in practice), then count
        unsigned long long v;
        int spin = 0;
        do {
            v = __hip_atomic_load(counter, __ATOMIC_RELAXED, __HIP_MEMORY_SCOPE_AGENT);
            if ((v >> 32) == (MAGIC >> 32)) break;
            __builtin_amdgcn_s_sleep(1);
        } while (++spin < (1 << 24));
        const unsigned long long old = __hip_atomic_fetch_add(counter, 1ull,
                                __ATOMIC_ACQ_REL, __HIP_MEMORY_SCOPE_AGENT);
        lastflag = ((unsigned)(old & 0xffffffffull) == gridDim.x - 1) ? 1 : 0;
    }
    __syncthreads();

    if (lastflag) {
        double a = 0, b = 0, c = 0;
        const int nb = (int)gridDim.x;
        for (int i = tid; i < nb; i += 256) {
            a += __hip_atomic_load(&partials[i * 3 + 0], __ATOMIC_ACQUIRE, __HIP_MEMORY_SCOPE_AGENT);
            b += __hip_atomic_load(&partials[i * 3 + 1], __ATOMIC_ACQUIRE, __HIP_MEMORY_SCOPE_AGENT);
            c += __hip_atomic_load(&partials[i * 3 + 2], __ATOMIC_ACQUIRE, __HIP_MEMORY_SCOPE_AGENT);
        }
        a = wave_reduce(a); b = wave_reduce(b); c = wave_reduce(c);
        if (lane == 0) { sred[0][wid] = a; sred[1][wid] = b; sred[2][wid] = c; }
        __syncthreads();
        if (tid == 0) {
            const double inv = 1.0 / (double)N;
            double s0 = 0, s1 = 0, s2 = 0;
            #pragma unroll
            for (int wv = 0; wv < 4; ++wv) { s0 += sred[0][wv]; s1 += sred[1][wv]; s2 += sred[2][wv]; }
            out[0] = (float)(s0 * inv);
            out[1] = (float)(s1 * inv);
            out[2] = (float)(s2 * inv);
        }
    }
}

extern "C" void kernel_launch(void* const* d_in, const int* in_sizes, int n_in,
                              void* d_out, int out_size, void* d_ws, size_t ws_size,
                              hipStream_t stream) {
    const float* tt = (const float*)d_in[0];
    const float* xx = (const float*)d_in[1];
    const float* tg = (const float*)d_in[2];
    const float* W1 = (const float*)d_in[3];
    const float* b1 = (const float*)d_in[4];
    const float* W2 = (const float*)d_in[5];
    const float* b2 = (const float*)d_in[6];
    const int N = in_sizes[0];

    const int npair = N >> 1;
    int blocks = (npair + 255) / 256;
    if (blocks < 1) blocks = 1;
    if (blocks > 1024) blocks = 1024;   // co-residency bound: 4 blocks/CU x 256 CUs
    while (32 + (size_t)blocks * 3 * sizeof(double) > ws_size && blocks > 1) blocks >>= 1;

    unsigned long long* counter = (unsigned long long*)d_ws;   // poison-proof ticket
    double* partials = (double*)((char*)d_ws + 32);

    surf_loss_fused<<<blocks, 256, 0, stream>>>(tt, xx, tg, W1, b1, W2, b2,
                                                partials, counter, (float*)d_out, N);
}

// Round 7
// 21.187 us; speedup vs baseline: 1.2431x; 1.2431x over previous
//
#include <hip/hip_runtime.h>
#include <cmath>

#define HDIM 128
typedef float f32x2 __attribute__((ext_vector_type(2)));

constexpr float EPSF = 1e-5f;
constexpr float K2L  = 2.8853900817779268f;   // 2*log2(e)
constexpr float L2E  = 1.4426950408889634f;   // log2(e)
constexpr float LN2  = 0.6931471805599453f;

__device__ inline float fast_rcp(float x) { return __builtin_amdgcn_rcpf(x); }

__device__ inline float fast_exp2(float x) {
#if __has_builtin(__builtin_amdgcn_exp2f)
    return __builtin_amdgcn_exp2f(x);
#else
    float r; asm("v_exp_f32 %0, %1" : "=v"(r) : "v"(x)); return r;
#endif
}

__device__ inline float fast_log2(float x) {
#if __has_builtin(__builtin_amdgcn_logf)
    return __builtin_amdgcn_logf(x);
#else
    float r; asm("v_log_f32 %0, %1" : "=v"(r) : "v"(x)); return r;
#endif
}

__device__ inline f32x2 splat2(float v) { return (f32x2){v, v}; }

__device__ inline f32x2 pk_fma(f32x2 a, f32x2 b, f32x2 c) {
#if __has_builtin(__builtin_elementwise_fma)
    return __builtin_elementwise_fma(a, b, c);
#else
    f32x2 r; r.x = fmaf(a.x, b.x, c.x); r.y = fmaf(a.y, b.y, c.y); return r;
#endif
}

__device__ inline double wave_reduce(double v) {
    #pragma unroll
    for (int off = 32; off > 0; off >>= 1)
        v += __shfl_down(v, off, 64);
    return v;
}

// True-scale epilogue: ut = u_t, ux = u_x, uxx = u_xx (no residual factors).
__device__ inline void point_epilogue(float u, float ut, float ux, float uxx,
                                      float x, float tgt,
                                      double& mspe, double& cal, double& bfly)
{
    const float q  = fast_exp2(-fabsf(u) * L2E);           // e^{-|u|}
    const float rp = fast_rcp(1.f + q);
    const float s  = (u >= 0.f) ? rp : q * rp;             // sigmoid(u)
    const float w_log  = fmaxf(u, 0.f) + LN2 * fast_log2(1.f + q);
    const float w_tail = q * fmaf(-0.5f, q, 1.f);          // softplus(u), u << 0
    const float w  = (u < -9.f) ? w_tail : w_log;

    const float w_t  = s * ut;
    const float w_x  = s * ux;
    const float w_xx = fmaf(s * (1.f - s), ux * ux, s * uxx);

    const float pe = (w - tgt) * fast_rcp(tgt + EPSF);
    mspe += (double)pe * (double)pe;

    const float ctm = fmaxf(-w_t, 0.f);
    cal += (double)ctm * (double)ctm;

    const float invw = fast_rcp(w);
    const float a1 = fmaf(-0.5f * x * w_x, invw, 1.f);
    const float g  = fmaf(0.5f, w_xx,
                     fmaf(a1, a1, -0.25f * w_x * (invw + 0.25f)));
    const float btm = fmaxf(-g, 0.f);
    bfly += (double)btm * (double)btm;
}

// R1 structure (two kernels, pair-packed points), strength-reduced inner loop:
//   r = 1/(1+e^{2z}); th = 1-2r; sech^2 = 4r(1-r)
//   u    = ubias - 2*S1,  S1  = sum v*r        (ubias = b2 + sum v)
//   u_t  = 4*AT,          AT  = sum (v*a)*rr   (rr = r*(1-r))
//   u_x  = 4*AX,          AX  = sum (v*c)*rr
//   u_xx = -8*AXX,        AXX = sum (v*c^2)*rr*th
__global__ __launch_bounds__(256, 4) void surf_loss_main(
    const float* __restrict__ tt, const float* __restrict__ xx,
    const float* __restrict__ tg,
    const float* __restrict__ W1, const float* __restrict__ b1,
    const float* __restrict__ W2, const float* __restrict__ b2,
    double* __restrict__ partials, int N)
{
    __shared__ float4 cs1[HDIM];  // (K2L*a, K2L*c, K2L*b, v)
    __shared__ float4 cs2[HDIM];  // (v*a, v*c, v*c*c, 0)
    __shared__ double sred[3][4];
    __shared__ float vsum_s;
    const int tid = threadIdx.x;
    for (int i = tid; i < HDIM; i += 256) {
        const float a = W1[i], c = W1[HDIM + i], b = b1[i], v = W2[i];
        cs1[i] = make_float4(K2L * a, K2L * c, K2L * b, v);
        cs2[i] = make_float4(v * a, v * c, v * c * c, 0.f);
    }
    __syncthreads();
    if (tid == 0) {
        float s = 0.f;
        for (int i = 0; i < HDIM; ++i) s += cs1[i].w;
        vsum_s = s;
    }
    __syncthreads();
    const float ubias = b2[0] + vsum_s;

    double mspe = 0.0, cal = 0.0, bfly = 0.0;

    const int npair = N >> 1;
    const f32x2* __restrict__ tt2 = (const f32x2*)tt;
    const f32x2* __restrict__ xx2 = (const f32x2*)xx;
    const f32x2* __restrict__ tg2 = (const f32x2*)tg;

    for (int p = blockIdx.x * 256 + tid; p < npair; p += gridDim.x * 256) {
        const f32x2 t2 = tt2[p], x2 = xx2[p], g2 = tg2[p];
        f32x2 S1  = splat2(0.f);
        f32x2 AT  = splat2(0.f);
        f32x2 AX  = splat2(0.f);
        f32x2 AXX = splat2(0.f);
        #pragma unroll 8
        for (int i = 0; i < HDIM; ++i) {
            const float4 k1 = cs1[i];     // uniform -> LDS broadcast, no conflict
            const float4 k2 = cs2[i];
            const f32x2 z  = pk_fma(t2, splat2(k1.x),
                              pk_fma(x2, splat2(k1.y), splat2(k1.z)));  // 2z*log2(e)
            f32x2 e;  e.x = fast_exp2(z.x); e.y = fast_exp2(z.y);       // e^{2z}
            const f32x2 ep = e + splat2(1.f);
            const float R  = fast_rcp(ep.x * ep.y);    // joint reciprocal
            f32x2 r;  r.x = R * ep.y;  r.y = R * ep.x; // 1/(1+e^{2z})
            const f32x2 rr = pk_fma(-r, r, r);                          // r(1-r)
            const f32x2 th = pk_fma(splat2(-2.f), r, splat2(1.f));      // tanh(z)
            const f32x2 s  = rr * th;
            S1  = pk_fma(splat2(k1.w), r,  S1);
            AT  = pk_fma(splat2(k2.x), rr, AT);
            AX  = pk_fma(splat2(k2.y), rr, AX);
            AXX = pk_fma(splat2(k2.z), s,  AXX);
        }
        point_epilogue(fmaf(-2.f, S1.x, ubias), 4.f * AT.x, 4.f * AX.x, -8.f * AXX.x,
                       x2.x, g2.x, mspe, cal, bfly);
        point_epilogue(fmaf(-2.f, S1.y, ubias), 4.f * AT.y, 4.f * AX.y, -8.f * AXX.y,
                       x2.y, g2.y, mspe, cal, bfly);
    }

    // odd-N tail: one scalar point
    if ((N & 1) && blockIdx.x == 0 && tid == 0) {
        const int idx = N - 1;
        const float t = tt[idx], x = xx[idx], tgt = tg[idx];
        float S1 = 0.f, AT = 0.f, AX = 0.f, AXX = 0.f;
        for (int i = 0; i < HDIM; ++i) {
            const float4 k1 = cs1[i];
            const float4 k2 = cs2[i];
            const float z  = fmaf(t, k1.x, fmaf(x, k1.y, k1.z));
            const float e  = fast_exp2(z);
            const float r  = fast_rcp(e + 1.f);
            const float rr = fmaf(-r, r, r);
            const float th = fmaf(-2.f, r, 1.f);
            S1  = fmaf(k1.w, r,  S1);
            AT  = fmaf(k2.x, rr, AT);
            AX  = fmaf(k2.y, rr, AX);
            AXX = fmaf(k2.z, rr * th, AXX);
        }
        point_epilogue(fmaf(-2.f, S1, ubias), 4.f * AT, 4.f * AX, -8.f * AXX,
                       x, tgt, mspe, cal, bfly);
    }

    double v0 = wave_reduce(mspe), v1 = wave_reduce(cal), v2 = wave_reduce(bfly);
    const int wid = tid >> 6, lane = tid & 63;
    if (lane == 0) { sred[0][wid] = v0; sred[1][wid] = v1; sred[2][wid] = v2; }
    __syncthreads();
    if (tid == 0) {
        double a = 0, b = 0, c = 0;
        #pragma unroll
        for (int wv = 0; wv < 4; ++wv) { a += sred[0][wv]; b += sred[1][wv]; c += sred[2][wv]; }
        partials[blockIdx.x * 3 + 0] = a;
        partials[blockIdx.x * 3 + 1] = b;
        partials[blockIdx.x * 3 + 2] = c;
    }
}

__global__ __launch_bounds__(256) void surf_loss_final(
    const double* __restrict__ partials, int nblocks, float* __restrict__ out, int N)
{
    const int tid = threadIdx.x;
    double a = 0, b = 0, c = 0;
    for (int i = tid; i < nblocks; i += 256) {
        a += partials[i * 3 + 0];
        b += partials[i * 3 + 1];
        c += partials[i * 3 + 2];
    }
    a = wave_reduce(a); b = wave_reduce(b); c = wave_reduce(c);
    __shared__ double sred[3][4];
    const int wid = tid >> 6, lane = tid & 63;
    if (lane == 0) { sred[0][wid] = a; sred[1][wid] = b; sred[2][wid] = c; }
    __syncthreads();
    if (tid == 0) {
        const double inv = 1.0 / (double)N;
        double s0 = 0, s1 = 0, s2 = 0;
        #pragma unroll
        for (int wv = 0; wv < 4; ++wv) { s0 += sred[0][wv]; s1 += sred[1][wv]; s2 += sred[2][wv]; }
        out[0] = (float)(s0 * inv);
        out[1] = (float)(s1 * inv);
        out[2] = (float)(s2 * inv);
    }
}

extern "C" void kernel_launch(void* const* d_in, const int* in_sizes, int n_in,
                              void* d_out, int out_size, void* d_ws, size_t ws_size,
                              hipStream_t stream) {
    const float* tt = (const float*)d_in[0];
    const float* xx = (const float*)d_in[1];
    const float* tg = (const float*)d_in[2];
    const float* W1 = (const float*)d_in[3];
    const float* b1 = (const float*)d_in[4];
    const float* W2 = (const float*)d_in[5];
    const float* b2 = (const float*)d_in[6];
    const int N = in_sizes[0];

    const int npair = N >> 1;
    int blocks = (npair + 255) / 256;
    if (blocks < 1) blocks = 1;
    if (blocks > 1024) blocks = 1024;
    while ((size_t)blocks * 3 * sizeof(double) > ws_size && blocks > 1) blocks >>= 1;

    double* partials = (double*)d_ws;
    surf_loss_main<<<blocks, 256, 0, stream>>>(tt, xx, tg, W1, b1, W2, b2, partials, N);
    surf_loss_final<<<1, 256, 0, stream>>>(partials, blocks, (float*)d_out, N);
}

// Round 8
// 20.278 us; speedup vs baseline: 1.2987x; 1.0448x over previous
//
#include <hip/hip_runtime.h>
#include <cmath>

#define HDIM 128
typedef float f32x2 __attribute__((ext_vector_type(2)));

constexpr float EPSF = 1e-5f;
constexpr float K2L  = 2.8853900817779268f;   // 2*log2(e)
constexpr float INVK = 0.34657359027997264f;  // ln(2)/2
constexpr float L2E  = 1.4426950408889634f;   // log2(e)
constexpr float LN2  = 0.6931471805599453f;
constexpr float UXXS = -2.0f * INVK * INVK;   // restores -2*c^2 scale in epilogue

__device__ inline float fast_rcp(float x) { return __builtin_amdgcn_rcpf(x); }

__device__ inline float fast_exp2(float x) {
#if __has_builtin(__builtin_amdgcn_exp2f)
    return __builtin_amdgcn_exp2f(x);
#else
    float r; asm("v_exp_f32 %0, %1" : "=v"(r) : "v"(x)); return r;
#endif
}

__device__ inline float fast_log2(float x) {
#if __has_builtin(__builtin_amdgcn_logf)
    return __builtin_amdgcn_logf(x);
#else
    float r; asm("v_log_f32 %0, %1" : "=v"(r) : "v"(x)); return r;
#endif
}

__device__ inline f32x2 splat2(float v) { return (f32x2){v, v}; }

__device__ inline f32x2 pk_fma(f32x2 a, f32x2 b, f32x2 c) {
#if __has_builtin(__builtin_elementwise_fma)
    return __builtin_elementwise_fma(a, b, c);
#else
    f32x2 r; r.x = fmaf(a.x, b.x, c.x); r.y = fmaf(a.y, b.y, c.y); return r;
#endif
}

__device__ inline double wave_reduce(double v) {
    #pragma unroll
    for (int off = 32; off > 0; off >>= 1)
        v += __shfl_down(v, off, 64);
    return v;
}

// ut,ux carry K2L scale; uxxp = +sum(wd*th*c'^2) carries K2L^2; UXXS restores -2/K2L^2.
__device__ inline void point_epilogue(float u, float ut, float ux, float uxxp,
                                      float x, float tgt,
                                      double& mspe, double& cal, double& bfly)
{
    const float q  = fast_exp2(-fabsf(u) * L2E);           // e^{-|u|}
    const float rp = fast_rcp(1.f + q);
    const float s  = (u >= 0.f) ? rp : q * rp;             // sigmoid(u)
    const float w_log  = fmaxf(u, 0.f) + LN2 * fast_log2(1.f + q);
    const float w_tail = q * fmaf(-0.5f, q, 1.f);          // softplus(u), u << 0
    const float w  = (u < -9.f) ? w_tail : w_log;

    const float utt  = ut * INVK;
    const float uxt  = ux * INVK;
    const float uxxt = uxxp * UXXS;
    const float w_t  = s * utt;
    const float w_x  = s * uxt;
    const float w_xx = fmaf(s * (1.f - s), uxt * uxt, s * uxxt);

    const float pe = (w - tgt) * fast_rcp(tgt + EPSF);
    mspe += (double)pe * (double)pe;

    const float ctm = fmaxf(-w_t, 0.f);
    cal += (double)ctm * (double)ctm;

    const float invw = fast_rcp(w);
    const float a1 = fmaf(-0.5f * x * w_x, invw, 1.f);
    const float g  = fmaf(0.5f, w_xx,
                     fmaf(a1, a1, -0.25f * w_x * (invw + 0.25f)));
    const float btm = fmaxf(-g, 0.f);
    bfly += (double)btm * (double)btm;
}

// R1 body (single float4/unit, pair-packed points) + joint reciprocal.
__global__ __launch_bounds__(256, 2) void surf_loss_main(
    const float* __restrict__ tt, const float* __restrict__ xx,
    const float* __restrict__ tg,
    const float* __restrict__ W1, const float* __restrict__ b1,
    const float* __restrict__ W2, const float* __restrict__ b2,
    double* __restrict__ partials, int N)
{
    __shared__ float4 cs[HDIM];   // (A', C', B', W2), A',C',B' pre-scaled by K2L
    __shared__ double sred[3][4];
    const int tid = threadIdx.x;
    for (int i = tid; i < HDIM; i += 256) {
        cs[i] = make_float4(W1[i] * K2L, W1[HDIM + i] * K2L, b1[i] * K2L, W2[i]);
    }
    __syncthreads();
    const float b2v = b2[0];

    double mspe = 0.0, cal = 0.0, bfly = 0.0;

    const int npair = N >> 1;
    const f32x2* __restrict__ tt2 = (const f32x2*)tt;
    const f32x2* __restrict__ xx2 = (const f32x2*)xx;
    const f32x2* __restrict__ tg2 = (const f32x2*)tg;

    for (int p = blockIdx.x * 256 + tid; p < npair; p += gridDim.x * 256) {
        const f32x2 t2 = tt2[p], x2 = xx2[p], g2 = tg2[p];
        f32x2 u2   = splat2(0.f);
        f32x2 ut2  = splat2(0.f);
        f32x2 ux2  = splat2(0.f);
        f32x2 uxx2 = splat2(0.f);
        #pragma unroll 8
        for (int i = 0; i < HDIM; ++i) {
            const float4 c = cs[i];       // uniform index -> LDS broadcast
            const f32x2 z  = pk_fma(t2, splat2(c.x),
                              pk_fma(x2, splat2(c.y), splat2(c.z)));  // 2z*log2(e)
            f32x2 e;  e.x = fast_exp2(z.x); e.y = fast_exp2(z.y);     // e^{2z}
            const f32x2 ep = e + splat2(1.f);
            const float R  = fast_rcp(ep.x * ep.y);    // joint reciprocal: 1 trans
            f32x2 r;  r.x = R * ep.y;  r.y = R * ep.x; // 1/(1+e^{2z})
            const f32x2 th = pk_fma(splat2(-2.f), r, splat2(1.f));    // tanh(z)
            const f32x2 d  = pk_fma(-th, th, splat2(1.f));            // sech^2(z)
            const f32x2 wd = d * splat2(c.w);
            u2   = pk_fma(th, splat2(c.w), u2);
            ut2  = pk_fma(wd, splat2(c.x), ut2);
            ux2  = pk_fma(wd, splat2(c.y), ux2);
            const f32x2 wt  = wd * th;
            const f32x2 wtc = wt * splat2(c.y);
            uxx2 = pk_fma(wtc, splat2(c.y), uxx2);                    // +sum wd*th*c'^2
        }
        point_epilogue(u2.x + b2v, ut2.x, ux2.x, uxx2.x, x2.x, g2.x, mspe, cal, bfly);
        point_epilogue(u2.y + b2v, ut2.y, ux2.y, uxx2.y, x2.y, g2.y, mspe, cal, bfly);
    }

    // odd-N tail: one scalar point
    if ((N & 1) && blockIdx.x == 0 && tid == 0) {
        const int idx = N - 1;
        const float t = tt[idx], x = xx[idx], tgt = tg[idx];
        float u = 0.f, ut = 0.f, ux = 0.f, uxx = 0.f;
        for (int i = 0; i < HDIM; ++i) {
            const float4 c = cs[i];
            const float zp = fmaf(t, c.x, fmaf(x, c.y, c.z));
            const float e  = fast_exp2(zp);
            const float r  = fast_rcp(e + 1.f);
            const float th = fmaf(-2.f, r, 1.f);
            const float d  = fmaf(-th, th, 1.f);
            const float wd = c.w * d;
            u   = fmaf(c.w, th, u);
            ut  = fmaf(wd, c.x, ut);
            ux  = fmaf(wd, c.y, ux);
            uxx = fmaf(wd * th * c.y, c.y, uxx);
        }
        point_epilogue(u + b2v, ut, ux, uxx, x, tgt, mspe, cal, bfly);
    }

    double v0 = wave_reduce(mspe), v1 = wave_reduce(cal), v2 = wave_reduce(bfly);
    const int wid = tid >> 6, lane = tid & 63;
    if (lane == 0) { sred[0][wid] = v0; sred[1][wid] = v1; sred[2][wid] = v2; }
    __syncthreads();
    if (tid == 0) {
        double a = 0, b = 0, c = 0;
        #pragma unroll
        for (int wv = 0; wv < 4; ++wv) { a += sred[0][wv]; b += sred[1][wv]; c += sred[2][wv]; }
        partials[blockIdx.x * 3 + 0] = a;
        partials[blockIdx.x * 3 + 1] = b;
        partials[blockIdx.x * 3 + 2] = c;
    }
}

__global__ __launch_bounds__(256) void surf_loss_final(
    const double* __restrict__ partials, int nblocks, float* __restrict__ out, int N)
{
    const int tid = threadIdx.x;
    double a = 0, b = 0, c = 0;
    for (int i = tid; i < nblocks; i += 256) {
        a += partials[i * 3 + 0];
        b += partials[i * 3 + 1];
        c += partials[i * 3 + 2];
    }
    a = wave_reduce(a); b = wave_reduce(b); c = wave_reduce(c);
    __shared__ double sred[3][4];
    const int wid = tid >> 6, lane = tid & 63;
    if (lane == 0) { sred[0][wid] = a; sred[1][wid] = b; sred[2][wid] = c; }
    __syncthreads();
    if (tid == 0) {
        const double inv = 1.0 / (double)N;
        double s0 = 0, s1 = 0, s2 = 0;
        #pragma unroll
        for (int wv = 0; wv < 4; ++wv) { s0 += sred[0][wv]; s1 += sred[1][wv]; s2 += sred[2][wv]; }
        out[0] = (float)(s0 * inv);
        out[1] = (float)(s1 * inv);
        out[2] = (float)(s2 * inv);
    }
}

extern "C" void kernel_launch(void* const* d_in, const int* in_sizes, int n_in,
                              void* d_out, int out_size, void* d_ws, size_t ws_size,
                              hipStream_t stream) {
    const float* tt = (const float*)d_in[0];
    const float* xx = (const float*)d_in[1];
    const float* tg = (const float*)d_in[2];
    const float* W1 = (const float*)d_in[3];
    const float* b1 = (const float*)d_in[4];
    const float* W2 = (const float*)d_in[5];
    const float* b2 = (const float*)d_in[6];
    const int N = in_sizes[0];

    const int npair = N >> 1;
    int blocks = (npair + 255) / 256;
    if (blocks < 1) blocks = 1;
    if (blocks > 1024) blocks = 1024;
    while ((size_t)blocks * 3 * sizeof(double) > ws_size && blocks > 1) blocks >>= 1;

    double* partials = (double*)d_ws;
    surf_loss_main<<<blocks, 256, 0, stream>>>(tt, xx, tg, W1, b1, W2, b2, partials, N);
    surf_loss_final<<<1, 256, 0, stream>>>(partials, blocks, (float*)d_out, N);
}